// Round 7
// baseline (163.039 us; speedup 1.0000x reference)
//
#include <hip/hip_runtime.h>

typedef __bf16 bf16x8 __attribute__((ext_vector_type(8)));
typedef float  f32x16 __attribute__((ext_vector_type(16)));

// fp32 -> bf16 bits, round-to-nearest-even
__device__ __forceinline__ unsigned short f2bf_bits(float f) {
    unsigned int u = __builtin_bit_cast(unsigned int, f);
    u += 0x7FFFu + ((u >> 16) & 1u);
    return (unsigned short)(u >> 16);
}

// One workgroup = one channel c, 8 images (2 per wave, 4 waves). grid = 192*4 = 768.
// Out[ho,wo] = sum_r sum_kw  Weff[25+r-ho, kw] * Xp_r[wo+kw]
// Single-phase row buffer per (wave,img): LDS ops of one wave process in order, so
// W(row i+1) issued after R(row i) is race-free — no double buffer, no barriers.
// Per-row schedule keeps every implied s_waitcnt a counted lgkmcnt <= 15:
//   [MFMA ks01 (waits R1, 8 newer)] [MFMA ks23 (waits R2, 0 newer)] [W(i+1):16] [R1(i+1):12] [R2(i+1):8]
__global__ void __launch_bounds__(256, 2) dw5_51_kernel(
    const float* __restrict__ x,
    const float* __restrict__ w5,
    const float* __restrict__ w51,
    float* __restrict__ out)
{
    // weights, granule-major: g=kw/8 (8) x 128 rows x 8 elems
    __shared__ unsigned short wlds[8 * 1024];        // 16384 B
    // row buffers: 4 waves x 2 imgs x (8 shift-copies x 136 elems)
    __shared__ unsigned short rowbuf[4][2][1088];    // 17408 B  (total 33792 B)

    const int tid = threadIdx.x;
    const int wg  = blockIdx.x;
    const int c   = wg >> 2;      // 0..191
    const int bg  = wg & 3;       // 0..3

    // ---- stage effective weights, reversed rows, granule-major ----
    {
        const int s    = tid >> 1;          // 0..127
        const int half = tid & 1;
        const int kh   = 88 - s;
        const bool rowok = (kh >= 0) && (kh <= 50);
        #pragma unroll
        for (int j = 0; j < 32; ++j) {
            const int kw = half * 32 + j;
            float v = 0.0f;
            if (rowok && kw <= 50) {
                v = w51[c * 2601 + kh * 51 + kw];
                if (kh >= 23 && kh < 28 && kw >= 23 && kw < 28)
                    v += w5[c * 25 + (kh - 23) * 5 + (kw - 23)];
            }
            wlds[(kw >> 3) * 1024 + s * 8 + (kw & 7)] = f2bf_bits(v);
        }
    }

    const int lane = tid & 63;
    const int wv   = tid >> 6;        // wave 0..3
    const int b0   = bg * 8 + wv * 2; // first image
    const int n32  = lane & 31;
    const int gg   = lane >> 5;
    const int q    = lane & 7;
    const int u8   = n32 >> 3;

    // zero this wave's row buffers (pads must stay 0)
    {
        unsigned int* z = (unsigned int*)&rowbuf[wv][0][0];
        #pragma unroll
        for (int i = 0; i < 17; ++i) z[lane + 64 * i] = 0u;
    }
    __syncthreads();

    const long ib0 = ((long)b0 * 192 + c) * 4096;
    const long ib1 = ib0 + 192L * 4096;
    const float* xr0 = x + ib0 + lane;
    const float* xr1 = x + ib1 + lane;

    const int bidx  = 136 * q + 8 * u8 + 8 * gg;  // B-read base; +16*t
    const int wbase = lane + 25;                  // write elem = wbase + 135*qq
    const int abase = gg * 1024 + n32 * 8;        // + srow*8 + ks*2048

    unsigned short* rb0 = &rowbuf[wv][0][0];
    unsigned short* rb1 = &rowbuf[wv][1][0];

    f32x16 acc[2][2][2] = {};     // [img][mtile][ntile]
    bf16x8 A[2][4];               // [mtile][ks]
    bf16x8 d0[6], d1[6];          // B frags per img

    auto R1 = [&](int r) {        // 12 reads: A[*][0..1] + d*[0..3]
        const int s0 = (63 - r) * 8 + abase;
        const int s1 = (95 - r) * 8 + abase;
        #pragma unroll
        for (int ks = 0; ks < 2; ++ks) {
            A[0][ks] = *(const bf16x8*)&wlds[s0 + ks * 2048];
            A[1][ks] = *(const bf16x8*)&wlds[s1 + ks * 2048];
        }
        #pragma unroll
        for (int t = 0; t < 4; ++t) {
            d0[t] = *(const bf16x8*)&rb0[bidx + 16 * t];
            d1[t] = *(const bf16x8*)&rb1[bidx + 16 * t];
        }
    };
    auto R2 = [&](int r) {        // 8 reads: A[*][2..3] + d*[4..5]
        const int s0 = (63 - r) * 8 + abase;
        const int s1 = (95 - r) * 8 + abase;
        #pragma unroll
        for (int ks = 2; ks < 4; ++ks) {
            A[0][ks] = *(const bf16x8*)&wlds[s0 + ks * 2048];
            A[1][ks] = *(const bf16x8*)&wlds[s1 + ks * 2048];
        }
        #pragma unroll
        for (int t = 4; t < 6; ++t) {
            d0[t] = *(const bf16x8*)&rb0[bidx + 16 * t];
            d1[t] = *(const bf16x8*)&rb1[bidx + 16 * t];
        }
    };
    auto MF1 = [&](int r) {       // ks 0,1 — waits only R1 (8 newer ops from R2)
        __builtin_amdgcn_s_setprio(1);
        if (r <= 56) {
            #pragma unroll
            for (int ks = 0; ks < 2; ++ks) {
                acc[0][0][0] = __builtin_amdgcn_mfma_f32_32x32x16_bf16(A[0][ks], d0[ks],     acc[0][0][0], 0, 0, 0);
                acc[0][0][1] = __builtin_amdgcn_mfma_f32_32x32x16_bf16(A[0][ks], d0[ks + 2], acc[0][0][1], 0, 0, 0);
                acc[1][0][0] = __builtin_amdgcn_mfma_f32_32x32x16_bf16(A[0][ks], d1[ks],     acc[1][0][0], 0, 0, 0);
                acc[1][0][1] = __builtin_amdgcn_mfma_f32_32x32x16_bf16(A[0][ks], d1[ks + 2], acc[1][0][1], 0, 0, 0);
            }
        }
        if (r >= 7) {
            #pragma unroll
            for (int ks = 0; ks < 2; ++ks) {
                acc[0][1][0] = __builtin_amdgcn_mfma_f32_32x32x16_bf16(A[1][ks], d0[ks],     acc[0][1][0], 0, 0, 0);
                acc[0][1][1] = __builtin_amdgcn_mfma_f32_32x32x16_bf16(A[1][ks], d0[ks + 2], acc[0][1][1], 0, 0, 0);
                acc[1][1][0] = __builtin_amdgcn_mfma_f32_32x32x16_bf16(A[1][ks], d1[ks],     acc[1][1][0], 0, 0, 0);
                acc[1][1][1] = __builtin_amdgcn_mfma_f32_32x32x16_bf16(A[1][ks], d1[ks + 2], acc[1][1][1], 0, 0, 0);
            }
        }
    };
    auto MF2 = [&](int r) {       // ks 2,3 — R2 retired during MF1, zero stall
        if (r <= 56) {
            #pragma unroll
            for (int ks = 2; ks < 4; ++ks) {
                acc[0][0][0] = __builtin_amdgcn_mfma_f32_32x32x16_bf16(A[0][ks], d0[ks],     acc[0][0][0], 0, 0, 0);
                acc[0][0][1] = __builtin_amdgcn_mfma_f32_32x32x16_bf16(A[0][ks], d0[ks + 2], acc[0][0][1], 0, 0, 0);
                acc[1][0][0] = __builtin_amdgcn_mfma_f32_32x32x16_bf16(A[0][ks], d1[ks],     acc[1][0][0], 0, 0, 0);
                acc[1][0][1] = __builtin_amdgcn_mfma_f32_32x32x16_bf16(A[0][ks], d1[ks + 2], acc[1][0][1], 0, 0, 0);
            }
        }
        if (r >= 7) {
            #pragma unroll
            for (int ks = 2; ks < 4; ++ks) {
                acc[0][1][0] = __builtin_amdgcn_mfma_f32_32x32x16_bf16(A[1][ks], d0[ks],     acc[0][1][0], 0, 0, 0);
                acc[0][1][1] = __builtin_amdgcn_mfma_f32_32x32x16_bf16(A[1][ks], d0[ks + 2], acc[0][1][1], 0, 0, 0);
                acc[1][1][0] = __builtin_amdgcn_mfma_f32_32x32x16_bf16(A[1][ks], d1[ks],     acc[1][1][0], 0, 0, 0);
                acc[1][1][1] = __builtin_amdgcn_mfma_f32_32x32x16_bf16(A[1][ks], d1[ks + 2], acc[1][1][1], 0, 0, 0);
            }
        }
        __builtin_amdgcn_s_setprio(0);
    };
    auto W = [&](float v0, float v1) {
        const unsigned short w0 = f2bf_bits(v0), w1 = f2bf_bits(v1);
        #pragma unroll
        for (int qq = 0; qq < 8; ++qq) {
            rb0[wbase + 135 * qq] = w0;
            rb1[wbase + 135 * qq] = w1;
        }
    };

    // ---- prologue: row 0 into LDS + fragments; xv = row 1 ----
    float xv0 = xr0[0], xv1 = xr1[0];
    W(xv0, xv1);
    R1(0);
    R2(0);
    xv0 = xr0[64]; xv1 = xr1[64];

    #pragma unroll 1
    for (int i = 0; i < 63; ++i) {
        MF1(i);
        MF2(i);
        __builtin_amdgcn_sched_barrier(0);    // keep W/R below the MFMA region
        W(xv0, xv1);                          // row i+1 (FIFO-after R(i): safe)
        R1(i + 1);
        R2(i + 1);
        if (i + 2 < 64) { xv0 = xr0[(i + 2) * 64]; xv1 = xr1[(i + 2) * 64]; }
        __builtin_amdgcn_sched_barrier(0);
    }
    MF1(63);
    MF2(63);

    // ---- epilogue: D layout (32x32): col = lane&31, row = (v&3) + 8*(v>>2) + 4*(lane>>5) ----
    float* outp0 = out + ib0;
    float* outp1 = out + ib1;
    #pragma unroll
    for (int v = 0; v < 16; ++v) {
        const int ho = (v & 3) + 8 * (v >> 2) + 4 * gg;
        outp0[ho * 64 + n32]             = acc[0][0][0][v];
        outp0[ho * 64 + n32 + 32]        = acc[0][0][1][v];
        outp0[(ho + 32) * 64 + n32]      = acc[0][1][0][v];
        outp0[(ho + 32) * 64 + n32 + 32] = acc[0][1][1][v];
        outp1[ho * 64 + n32]             = acc[1][0][0][v];
        outp1[ho * 64 + n32 + 32]        = acc[1][0][1][v];
        outp1[(ho + 32) * 64 + n32]      = acc[1][1][0][v];
        outp1[(ho + 32) * 64 + n32 + 32] = acc[1][1][1][v];
    }
}

extern "C" void kernel_launch(void* const* d_in, const int* in_sizes, int n_in,
                              void* d_out, int out_size, void* d_ws, size_t ws_size,
                              hipStream_t stream) {
    (void)in_sizes; (void)n_in; (void)d_ws; (void)ws_size; (void)out_size;
    const float* x   = (const float*)d_in[0];
    const float* w5  = (const float*)d_in[1];
    const float* w51 = (const float*)d_in[2];
    float* out = (float*)d_out;
    dim3 grid(192 * 4), block(256);
    hipLaunchKernelGGL(dw5_51_kernel, grid, block, 0, stream, x, w5, w51, out);
}

// Round 8
// 143.804 us; speedup vs baseline: 1.1338x; 1.1338x over previous
//
#include <hip/hip_runtime.h>

typedef __bf16 bf16x8 __attribute__((ext_vector_type(8)));
typedef float  f32x16 __attribute__((ext_vector_type(16)));

// fp32 -> bf16 bits, round-to-nearest-even
__device__ __forceinline__ unsigned short f2bf_bits(float f) {
    unsigned int u = __builtin_bit_cast(unsigned int, f);
    u += 0x7FFFu + ((u >> 16) & 1u);
    return (unsigned short)(u >> 16);
}

// One workgroup = one channel c, 4 images (1 per wave). grid = 192*8 = 1536.
// Regs ~145 -> 3 waves/SIMD -> 3 blocks resident/CU, 6 total = 2 even rounds.
// Single-phase row buffer per wave: a wave's LDS ops process in order, so
// W(row i+1) issued after R(row i) is race-free (no double buffer, no barriers).
// Per-row schedule, all waits counted (<=15):
//   [MF1 ks01 | lgkmcnt(6)] [MF2 ks23 | lgkmcnt(0)] [W(i+1):8] [R1(i+1):8] [R2(i+1):6]
__global__ void __launch_bounds__(256, 3) dw5_51_kernel(
    const float* __restrict__ x,
    const float* __restrict__ w5,
    const float* __restrict__ w51,
    float* __restrict__ out)
{
    // weights, granule-major: g=kw/8 (8) x 128 rows x 8 elems
    __shared__ unsigned short wlds[8 * 1024];        // 16384 B
    // row buffers: 4 waves x (8 shift-copies x 136 elems), single phase
    __shared__ unsigned short rowbuf[4][1088];       // 8704 B   (total 25088 B)

    const int tid = threadIdx.x;
    const int wg  = blockIdx.x;
    const int c   = wg >> 3;      // 0..191
    const int bg  = wg & 7;       // 0..7

    // ---- stage effective weights, reversed rows, granule-major ----
    {
        const int s    = tid >> 1;          // 0..127
        const int half = tid & 1;
        const int kh   = 88 - s;
        const bool rowok = (kh >= 0) && (kh <= 50);
        #pragma unroll
        for (int j = 0; j < 32; ++j) {
            const int kw = half * 32 + j;
            float v = 0.0f;
            if (rowok && kw <= 50) {
                v = w51[c * 2601 + kh * 51 + kw];
                if (kh >= 23 && kh < 28 && kw >= 23 && kw < 28)
                    v += w5[c * 25 + (kh - 23) * 5 + (kw - 23)];
            }
            wlds[(kw >> 3) * 1024 + s * 8 + (kw & 7)] = f2bf_bits(v);
        }
    }

    const int lane = tid & 63;
    const int wv   = tid >> 6;        // wave 0..3
    const int b    = bg * 4 + wv;     // batch 0..31
    const int n32  = lane & 31;
    const int gg   = lane >> 5;
    const int q    = lane & 7;
    const int u8   = n32 >> 3;

    // zero this wave's row buffer (pads must stay 0)
    {
        unsigned int* z = (unsigned int*)&rowbuf[wv][0];
        #pragma unroll
        for (int i = 0; i < 8; ++i) z[lane + 64 * i] = 0u;
        if (lane < 32) z[lane + 512] = 0u;
    }
    __syncthreads();

    const long imgbase = ((long)b * 192 + c) * 4096;
    const float* xrow = x + imgbase + lane;

    const int bidx  = 136 * q + 8 * u8 + 8 * gg;  // B-read base; +16*t, t=0..5
    const int wbase = lane + 25;                  // write elem = wbase + 135*qq
    const int abase = gg * 1024 + n32 * 8;        // + srow*8 + ks*2048

    unsigned short* rb = &rowbuf[wv][0];

    f32x16 acc00 = {}, acc01 = {}, acc10 = {}, acc11 = {};
    bf16x8 A[2][4];               // [mtile][ks]
    bf16x8 d[6];

    auto R1 = [&](int r) {        // 8 reads: A[*][0..1] + d[0..3]
        const int s0 = (63 - r) * 8 + abase;
        const int s1 = (95 - r) * 8 + abase;
        #pragma unroll
        for (int ks = 0; ks < 2; ++ks) {
            A[0][ks] = *(const bf16x8*)&wlds[s0 + ks * 2048];
            A[1][ks] = *(const bf16x8*)&wlds[s1 + ks * 2048];
        }
        #pragma unroll
        for (int t = 0; t < 4; ++t) d[t] = *(const bf16x8*)&rb[bidx + 16 * t];
    };
    auto R2 = [&](int r) {        // 6 reads: A[*][2..3] + d[4..5]
        const int s0 = (63 - r) * 8 + abase;
        const int s1 = (95 - r) * 8 + abase;
        #pragma unroll
        for (int ks = 2; ks < 4; ++ks) {
            A[0][ks] = *(const bf16x8*)&wlds[s0 + ks * 2048];
            A[1][ks] = *(const bf16x8*)&wlds[s1 + ks * 2048];
        }
        #pragma unroll
        for (int t = 4; t < 6; ++t) d[t] = *(const bf16x8*)&rb[bidx + 16 * t];
    };
    auto MF1 = [&](int r) {       // ks 0,1 — implied wait: lgkmcnt(6)
        __builtin_amdgcn_s_setprio(1);
        if (r <= 56) {
            #pragma unroll
            for (int ks = 0; ks < 2; ++ks) {
                acc00 = __builtin_amdgcn_mfma_f32_32x32x16_bf16(A[0][ks], d[ks],     acc00, 0, 0, 0);
                acc01 = __builtin_amdgcn_mfma_f32_32x32x16_bf16(A[0][ks], d[ks + 2], acc01, 0, 0, 0);
            }
        }
        if (r >= 7) {
            #pragma unroll
            for (int ks = 0; ks < 2; ++ks) {
                acc10 = __builtin_amdgcn_mfma_f32_32x32x16_bf16(A[1][ks], d[ks],     acc10, 0, 0, 0);
                acc11 = __builtin_amdgcn_mfma_f32_32x32x16_bf16(A[1][ks], d[ks + 2], acc11, 0, 0, 0);
            }
        }
    };
    auto MF2 = [&](int r) {       // ks 2,3 — implied wait: lgkmcnt(0), retired under MF1
        if (r <= 56) {
            #pragma unroll
            for (int ks = 2; ks < 4; ++ks) {
                acc00 = __builtin_amdgcn_mfma_f32_32x32x16_bf16(A[0][ks], d[ks],     acc00, 0, 0, 0);
                acc01 = __builtin_amdgcn_mfma_f32_32x32x16_bf16(A[0][ks], d[ks + 2], acc01, 0, 0, 0);
            }
        }
        if (r >= 7) {
            #pragma unroll
            for (int ks = 2; ks < 4; ++ks) {
                acc10 = __builtin_amdgcn_mfma_f32_32x32x16_bf16(A[1][ks], d[ks],     acc10, 0, 0, 0);
                acc11 = __builtin_amdgcn_mfma_f32_32x32x16_bf16(A[1][ks], d[ks + 2], acc11, 0, 0, 0);
            }
        }
        __builtin_amdgcn_s_setprio(0);
    };
    auto W = [&](float v) {
        const unsigned short w0 = f2bf_bits(v);
        #pragma unroll
        for (int qq = 0; qq < 8; ++qq) rb[wbase + 135 * qq] = w0;
    };

    // ---- prologue: row 0 into LDS + fragments; xv = row 1 ----
    float xv = xrow[0];
    W(xv);
    R1(0);
    R2(0);
    xv = xrow[64];

    #pragma unroll 1
    for (int i = 0; i < 63; ++i) {
        MF1(i);
        MF2(i);
        __builtin_amdgcn_sched_barrier(0);    // keep W/R below the MFMA region
        W(xv);                                // row i+1 (FIFO-after R(i): safe)
        R1(i + 1);
        R2(i + 1);
        if (i + 2 < 64) xv = xrow[(i + 2) * 64];
        __builtin_amdgcn_sched_barrier(0);
    }
    MF1(63);
    MF2(63);

    // ---- epilogue: D layout (32x32): col = lane&31, row = (v&3) + 8*(v>>2) + 4*(lane>>5) ----
    float* outp = out + imgbase;
    #pragma unroll
    for (int v = 0; v < 16; ++v) {
        const int ho = (v & 3) + 8 * (v >> 2) + 4 * gg;
        outp[ho * 64 + n32]             = acc00[v];
        outp[ho * 64 + n32 + 32]        = acc01[v];
        outp[(ho + 32) * 64 + n32]      = acc10[v];
        outp[(ho + 32) * 64 + n32 + 32] = acc11[v];
    }
}

extern "C" void kernel_launch(void* const* d_in, const int* in_sizes, int n_in,
                              void* d_out, int out_size, void* d_ws, size_t ws_size,
                              hipStream_t stream) {
    (void)in_sizes; (void)n_in; (void)d_ws; (void)ws_size; (void)out_size;
    const float* x   = (const float*)d_in[0];
    const float* w5  = (const float*)d_in[1];
    const float* w51 = (const float*)d_in[2];
    float* out = (float*)d_out;
    dim3 grid(192 * 8), block(256);
    hipLaunchKernelGGL(dw5_51_kernel, grid, block, 0, stream, x, w5, w51, out);
}

// Round 9
// 141.746 us; speedup vs baseline: 1.1502x; 1.0145x over previous
//
#include <hip/hip_runtime.h>

typedef __bf16 bf16x4 __attribute__((ext_vector_type(4)));
typedef __bf16 bf16x8 __attribute__((ext_vector_type(8)));
typedef float  f32x16 __attribute__((ext_vector_type(16)));

// fp32 -> bf16 bits, round-to-nearest-even
__device__ __forceinline__ unsigned short f2bf_bits(float f) {
    unsigned int u = __builtin_bit_cast(unsigned int, f);
    u += 0x7FFFu + ((u >> 16) & 1u);
    return (unsigned short)(u >> 16);
}

// One workgroup = one channel c, 8 batches (one per wave), grid 192*4 = 768 = 3 blocks/CU.
// Out[ho,wo] = sum_r sum_kw  Weff[25+r-ho, kw] * Xp_r[wo+kw]   (Xp = row padded by 25)
// Per input row r: D[m=ho][n=wo] += A[m][kw] * B[kw][n]
//   A[m][kw] = Weff[25+r-ho0-m][kw]  (granule-major LDS, b128 reads)
//   B[kw][n] = Xp_r[n+kw]            (4 shift-copies, stride 144 shorts, 2x ds_read_b64 per frag)
// Port work/img-row: 8 b128 + 12 b64 + 4 b16-writes = ~192 cyc (was 216 with 8 copies + b128).
__global__ void __launch_bounds__(512) dw5_51_kernel(
    const float* __restrict__ x,
    const float* __restrict__ w5,
    const float* __restrict__ w51,
    float* __restrict__ out)
{
    // weights, granule-major: granule g (kw/8) x 128 rows x 8 elems -> A-reads lane-stride 16B
    __shared__ unsigned short wlds[8 * 1024];                       // 16384 B
    // row buffers: 8 waves x 2 phases x (4 copies x 144 elems)
    __shared__ alignas(16) unsigned short rowbuf[8][2][576];        // 18432 B (total 34816 B)

    const int tid = threadIdx.x;
    const int wg  = blockIdx.x;
    const int c   = wg >> 2;      // 0..191
    const int bg  = wg & 3;       // 0..3

    // ---- stage effective weights, reversed rows, granule-major ----
    // LDS row s holds Weff row kh = 88 - s (valid kh in [0,51)); elem kw at wlds[(kw>>3)*1024 + s*8 + (kw&7)]
    {
        const int s   = tid >> 2;           // 0..127
        const int qtr = tid & 3;
        const int kh  = 88 - s;
        const bool rowok = (kh >= 0) && (kh <= 50);
        #pragma unroll
        for (int i = 0; i < 16; ++i) {
            const int kw = qtr * 16 + i;
            float v = 0.0f;
            if (rowok && kw <= 50) {
                v = w51[c * 2601 + kh * 51 + kw];
                if (kh >= 23 && kh < 28 && kw >= 23 && kw < 28)
                    v += w5[c * 25 + (kh - 23) * 5 + (kw - 23)];
            }
            wlds[(kw >> 3) * 1024 + s * 8 + (kw & 7)] = f2bf_bits(v);
        }
    }

    const int lane = tid & 63;
    const int wv   = tid >> 6;        // wave id 0..7
    const int b    = bg * 8 + wv;     // batch 0..31
    const int n32  = lane & 31;       // MFMA m/n lane index
    const int gg   = lane >> 5;       // k-group
    const int cpy  = lane & 3;        // shift-copy selector (s mod 4)
    const int u8   = n32 >> 3;        // n32 bits [4:3]
    const int v4   = (n32 >> 2) & 1;  // n32 bit [2]

    // zero this wave's row buffers (pad regions must be 0; data region rewritten every r)
    {
        unsigned int* z = (unsigned int*)&rowbuf[wv][0][0];
        #pragma unroll
        for (int i = 0; i < 9; ++i) z[lane + 64 * i] = 0u;   // 9*64 = 576 dwords = 2304 B
    }
    __syncthreads();

    const long imgbase = ((long)b * 192 + c) * 4096;
    const float* xrow = x + imgbase + lane;
    float* outp = out + imgbase;

    // B-read base (shorts): copy cpy at 144*cpy; within-copy slot 8*u8 + 4*v4 + 8*gg; +16*t +4*h immediates
    const int bidx = 144 * cpy + 8 * u8 + 4 * v4 + 8 * gg;
    unsigned short* rb0 = &rowbuf[wv][0][0];
    unsigned short* rb1 = &rowbuf[wv][1][0];
    // write: elem e = lane+25 goes to copy c at addr e + 143*c
    const int wbase = lane + 25;

    f32x16 acc00 = {}, acc01 = {}, acc10 = {}, acc11 = {};

    const int abase = gg * 1024 + n32 * 8;   // + srow*8 + ks*2048

    auto compute = [&](const unsigned short* __restrict__ rb, int r) {
        bf16x8 d[6];
        #pragma unroll
        for (int t = 0; t < 6; ++t) {
            const bf16x4 lo = *(const bf16x4*)&rb[bidx + 16 * t];
            const bf16x4 hi = *(const bf16x4*)&rb[bidx + 16 * t + 4];
            d[t] = __builtin_shufflevector(lo, hi, 0, 1, 2, 3, 4, 5, 6, 7);
        }
        if (r <= 56) {               // m-tile 0 (ho 0..31) active
            const int ai = abase + (63 - r) * 8;
            #pragma unroll
            for (int ks = 0; ks < 4; ++ks) {
                const bf16x8 Af = *(const bf16x8*)&wlds[ai + ks * 2048];
                acc00 = __builtin_amdgcn_mfma_f32_32x32x16_bf16(Af, d[ks],     acc00, 0, 0, 0);
                acc01 = __builtin_amdgcn_mfma_f32_32x32x16_bf16(Af, d[ks + 2], acc01, 0, 0, 0);
            }
        }
        if (r >= 7) {                // m-tile 1 (ho 32..63) active
            const int ai = abase + (95 - r) * 8;
            #pragma unroll
            for (int ks = 0; ks < 4; ++ks) {
                const bf16x8 Af = *(const bf16x8*)&wlds[ai + ks * 2048];
                acc10 = __builtin_amdgcn_mfma_f32_32x32x16_bf16(Af, d[ks],     acc10, 0, 0, 0);
                acc11 = __builtin_amdgcn_mfma_f32_32x32x16_bf16(Af, d[ks + 2], acc11, 0, 0, 0);
            }
        }
    };
    auto writerow = [&](unsigned short* p, float v) {
        const unsigned short w0 = f2bf_bits(v);
        #pragma unroll
        for (int cc = 0; cc < 4; ++cc) p[wbase + 143 * cc] = w0;
    };

    // prologue: row 0 -> buf0, prefetch row 1
    float xv = xrow[0];
    writerow(rb0, xv);
    xv = xrow[64];

    #pragma unroll 1
    for (int rr = 0; rr < 64; rr += 2) {
        // ---- phase 0: write row rr+1 -> buf1, compute row rr from buf0 ----
        {
            writerow(rb1, xv);
            if (rr + 2 < 64) xv = xrow[(rr + 2) * 64];
            compute(rb0, rr);
        }
        // ---- phase 1: write row rr+2 -> buf0, compute row rr+1 from buf1 ----
        {
            if (rr + 2 < 64) {
                writerow(rb0, xv);
                if (rr + 3 < 64) xv = xrow[(rr + 3) * 64];
            }
            compute(rb1, rr + 1);
        }
    }

    // ---- epilogue: D layout (32x32): col = lane&31, row = (v&3) + 8*(v>>2) + 4*(lane>>5) ----
    #pragma unroll
    for (int v = 0; v < 16; ++v) {
        const int ho = (v & 3) + 8 * (v >> 2) + 4 * gg;
        outp[ho * 64 + n32]             = acc00[v];
        outp[ho * 64 + n32 + 32]        = acc01[v];
        outp[(ho + 32) * 64 + n32]      = acc10[v];
        outp[(ho + 32) * 64 + n32 + 32] = acc11[v];
    }
}

extern "C" void kernel_launch(void* const* d_in, const int* in_sizes, int n_in,
                              void* d_out, int out_size, void* d_ws, size_t ws_size,
                              hipStream_t stream) {
    (void)in_sizes; (void)n_in; (void)d_ws; (void)ws_size; (void)out_size;
    const float* x   = (const float*)d_in[0];
    const float* w5  = (const float*)d_in[1];
    const float* w51 = (const float*)d_in[2];
    float* out = (float*)d_out;
    dim3 grid(192 * 4), block(512);
    hipLaunchKernelGGL(dw5_51_kernel, grid, block, 0, stream, x, w5, w51, out);
}

// Round 10
// 140.308 us; speedup vs baseline: 1.1620x; 1.0103x over previous
//
#include <hip/hip_runtime.h>

typedef __bf16 bf16x4 __attribute__((ext_vector_type(4)));
typedef __bf16 bf16x8 __attribute__((ext_vector_type(8)));
typedef float  f32x16 __attribute__((ext_vector_type(16)));

// fp32 -> bf16 bits, round-to-nearest-even
__device__ __forceinline__ unsigned short f2bf_bits(float f) {
    unsigned int u = __builtin_bit_cast(unsigned int, f);
    u += 0x7FFFu + ((u >> 16) & 1u);
    return (unsigned short)(u >> 16);
}

// One workgroup = one channel c, 4 images (1 per wave). grid = 192*8 = 1536.
// (256,3): ~134 total regs -> 3 waves/SIMD -> 3 blocks/CU -> 1536/(256*3) = 2 EVEN rounds.
// Single-phase row buffer (wave-FIFO makes W(i+1)-after-R(i) safe), b64-4copy B layout
// (conflict-free, R9-verified). Cross-iteration register pipeline (R8-verified structure):
//   loop i: [MF1(i) | lgkm(8)] [MF2(i) | lgkm(0)] || fence || [W(i+1):4] [R1(i+1):12] [R2(i+1):8] || fence
__global__ void __launch_bounds__(256, 3) dw5_51_kernel(
    const float* __restrict__ x,
    const float* __restrict__ w5,
    const float* __restrict__ w51,
    float* __restrict__ out)
{
    // weights, granule-major: g=kw/8 (8) x 128 rows x 8 elems
    __shared__ unsigned short wlds[8 * 1024];              // 16384 B
    // row buffers: 4 waves x (4 shift-copies x 144 elems), single phase
    __shared__ alignas(16) unsigned short rowbuf[4][576];  // 4608 B (total 20992 B)

    const int tid = threadIdx.x;
    const int wg  = blockIdx.x;
    const int c   = wg >> 3;      // 0..191
    const int bg  = wg & 7;       // 0..7

    // ---- stage effective weights, reversed rows, granule-major ----
    // LDS row s holds Weff row kh = 88 - s; elem kw at wlds[(kw>>3)*1024 + s*8 + (kw&7)]
    {
        const int s    = tid >> 1;          // 0..127
        const int half = tid & 1;
        const int kh   = 88 - s;
        const bool rowok = (kh >= 0) && (kh <= 50);
        #pragma unroll
        for (int j = 0; j < 32; ++j) {
            const int kw = half * 32 + j;
            float v = 0.0f;
            if (rowok && kw <= 50) {
                v = w51[c * 2601 + kh * 51 + kw];
                if (kh >= 23 && kh < 28 && kw >= 23 && kw < 28)
                    v += w5[c * 25 + (kh - 23) * 5 + (kw - 23)];
            }
            wlds[(kw >> 3) * 1024 + s * 8 + (kw & 7)] = f2bf_bits(v);
        }
    }

    const int lane = tid & 63;
    const int wv   = tid >> 6;        // wave 0..3
    const int b    = bg * 4 + wv;     // batch 0..31
    const int n32  = lane & 31;       // MFMA m/n lane index
    const int gg   = lane >> 5;       // k-group
    const int cpy  = lane & 3;        // shift-copy selector (n32 mod 4)
    const int u8   = n32 >> 3;
    const int v4   = (n32 >> 2) & 1;

    // zero this wave's row buffer (pads must stay 0; data slots rewritten every row)
    {
        unsigned int* z = (unsigned int*)&rowbuf[wv][0];
        #pragma unroll
        for (int i = 0; i < 4; ++i) z[lane + 64 * i] = 0u;   // 256 dwords
        if (lane < 32) z[256 + lane] = 0u;                    // + 32 = 288 dwords = 576 shorts
    }
    __syncthreads();

    const long imgbase = ((long)b * 192 + c) * 4096;
    const float* xrow = x + imgbase + lane;

    // B-read base (shorts): copy cpy at 144*cpy; slot 8*u8 + 4*v4 + 8*gg; +16*t, +4 immediates
    // copy_c[slot s] = Xp[s + c]  =>  lane reads Xp[(8u8+4v4+cpy) + 8gg + 16t ...] = Xp[n32 + 8gg + 16t]
    const int bidx  = 144 * cpy + 8 * u8 + 4 * v4 + 8 * gg;
    const int wbase = lane + 25;                 // write: copy cc at elem wbase + 143*cc
    const int abase = gg * 1024 + n32 * 8;       // + srow*8 + ks*2048

    unsigned short* rb = &rowbuf[wv][0];

    f32x16 acc00 = {}, acc01 = {}, acc10 = {}, acc11 = {};
    bf16x8 A[2][4];               // [mtile][ks]
    bf16x4 dl[6], dh[6];          // B frag halves (2 x b64 per fragment)

    auto R1 = [&](int r) {        // 12 reads: A[*][0..1] (4 b128) + d[0..3] halves (8 b64)
        const int s0 = (63 - r) * 8 + abase;
        const int s1 = (95 - r) * 8 + abase;
        #pragma unroll
        for (int ks = 0; ks < 2; ++ks) {
            A[0][ks] = *(const bf16x8*)&wlds[s0 + ks * 2048];
            A[1][ks] = *(const bf16x8*)&wlds[s1 + ks * 2048];
        }
        #pragma unroll
        for (int t = 0; t < 4; ++t) {
            dl[t] = *(const bf16x4*)&rb[bidx + 16 * t];
            dh[t] = *(const bf16x4*)&rb[bidx + 16 * t + 4];
        }
    };
    auto R2 = [&](int r) {        // 8 reads: A[*][2..3] (4 b128) + d[4..5] halves (4 b64)
        const int s0 = (63 - r) * 8 + abase;
        const int s1 = (95 - r) * 8 + abase;
        #pragma unroll
        for (int ks = 2; ks < 4; ++ks) {
            A[0][ks] = *(const bf16x8*)&wlds[s0 + ks * 2048];
            A[1][ks] = *(const bf16x8*)&wlds[s1 + ks * 2048];
        }
        #pragma unroll
        for (int t = 4; t < 6; ++t) {
            dl[t] = *(const bf16x4*)&rb[bidx + 16 * t];
            dh[t] = *(const bf16x4*)&rb[bidx + 16 * t + 4];
        }
    };
    auto D = [&](int t) -> bf16x8 {
        return __builtin_shufflevector(dl[t], dh[t], 0, 1, 2, 3, 4, 5, 6, 7);
    };
    auto MF1 = [&](int r) {       // ks 0,1 — implied wait lgkmcnt(8) (R2 still outstanding)
        __builtin_amdgcn_s_setprio(1);
        if (r <= 56) {
            #pragma unroll
            for (int ks = 0; ks < 2; ++ks) {
                acc00 = __builtin_amdgcn_mfma_f32_32x32x16_bf16(A[0][ks], D(ks),     acc00, 0, 0, 0);
                acc01 = __builtin_amdgcn_mfma_f32_32x32x16_bf16(A[0][ks], D(ks + 2), acc01, 0, 0, 0);
            }
        }
        if (r >= 7) {
            #pragma unroll
            for (int ks = 0; ks < 2; ++ks) {
                acc10 = __builtin_amdgcn_mfma_f32_32x32x16_bf16(A[1][ks], D(ks),     acc10, 0, 0, 0);
                acc11 = __builtin_amdgcn_mfma_f32_32x32x16_bf16(A[1][ks], D(ks + 2), acc11, 0, 0, 0);
            }
        }
    };
    auto MF2 = [&](int r) {       // ks 2,3 — implied wait lgkmcnt(0), retired under MF1
        if (r <= 56) {
            #pragma unroll
            for (int ks = 2; ks < 4; ++ks) {
                acc00 = __builtin_amdgcn_mfma_f32_32x32x16_bf16(A[0][ks], D(ks),     acc00, 0, 0, 0);
                acc01 = __builtin_amdgcn_mfma_f32_32x32x16_bf16(A[0][ks], D(ks + 2), acc01, 0, 0, 0);
            }
        }
        if (r >= 7) {
            #pragma unroll
            for (int ks = 2; ks < 4; ++ks) {
                acc10 = __builtin_amdgcn_mfma_f32_32x32x16_bf16(A[1][ks], D(ks),     acc10, 0, 0, 0);
                acc11 = __builtin_amdgcn_mfma_f32_32x32x16_bf16(A[1][ks], D(ks + 2), acc11, 0, 0, 0);
            }
        }
        __builtin_amdgcn_s_setprio(0);
    };
    auto W = [&](float v) {       // 4 b16 writes
        const unsigned short w0 = f2bf_bits(v);
        #pragma unroll
        for (int cc = 0; cc < 4; ++cc) rb[wbase + 143 * cc] = w0;
    };

    // ---- prologue: row 0 into LDS + fragments; xv = row 1 ----
    float xv = xrow[0];
    W(xv);
    R1(0);
    R2(0);
    xv = xrow[64];

    #pragma unroll 1
    for (int i = 0; i < 63; ++i) {
        MF1(i);
        MF2(i);
        __builtin_amdgcn_sched_barrier(0);    // keep W/R below the MFMA region
        W(xv);                                // row i+1 (wave-FIFO after R(i): safe)
        R1(i + 1);
        R2(i + 1);
        if (i + 2 < 64) xv = xrow[(i + 2) * 64];
        __builtin_amdgcn_sched_barrier(0);
    }
    MF1(63);
    MF2(63);

    // ---- epilogue: D layout (32x32): col = lane&31, row = (v&3) + 8*(v>>2) + 4*(lane>>5) ----
    float* outp = out + imgbase;
    #pragma unroll
    for (int v = 0; v < 16; ++v) {
        const int ho = (v & 3) + 8 * (v >> 2) + 4 * gg;
        outp[ho * 64 + n32]             = acc00[v];
        outp[ho * 64 + n32 + 32]        = acc01[v];
        outp[(ho + 32) * 64 + n32]      = acc10[v];
        outp[(ho + 32) * 64 + n32 + 32] = acc11[v];
    }
}

extern "C" void kernel_launch(void* const* d_in, const int* in_sizes, int n_in,
                              void* d_out, int out_size, void* d_ws, size_t ws_size,
                              hipStream_t stream) {
    (void)in_sizes; (void)n_in; (void)d_ws; (void)ws_size; (void)out_size;
    const float* x   = (const float*)d_in[0];
    const float* w5  = (const float*)d_in[1];
    const float* w51 = (const float*)d_in[2];
    float* out = (float*)d_out;
    dim3 grid(192 * 8), block(256);
    hipLaunchKernelGGL(dw5_51_kernel, grid, block, 0, stream, x, w5, w51, out);
}